// Round 20
// baseline (3062.163 us; speedup 1.0000x reference)
//
#include <hip/hip_runtime.h>

// Paraformer-large streaming decoder dims (CKV derived at runtime from in_sizes)
constexpr int LAY = 16, HID = 512, FF = 2048, NHD = 4, DKH = 128, KW = 11,
              VOC = 8404, TT = 64, SEQ = 2048, LBN = 256;

// LDS XOR swizzle (proven r13): kills 8-way store conflicts
#define SWZ(row, e) ((e) ^ ((((row) >> 2) & 7) << 2))

// ---------------- diagnostic: write value to 64 floats ----------------
__global__ void diag_k(float* __restrict__ p, float v) { p[threadIdx.x] = v; }

// ---- fused split-K reduce + bias/res/relu + LayerNorm (one block per row) --
__global__ __launch_bounds__(256) void redln_k(
    const float* __restrict__ P, int N, int nch,
    const float* __restrict__ bias, const float* __restrict__ res, int relu,
    const float* __restrict__ g, const float* __restrict__ b,
    float* __restrict__ out1, float* __restrict__ out2) {
  __shared__ float buf[2048];
  __shared__ float red[256];
  const int m = blockIdx.x, tid = threadIdx.x;
  float s = 0.f;
  for (int n = tid; n < N; n += 256) {
    const float* p = P + (size_t)m * N + n;
    float v = 0.f;
    for (int c = 0; c < nch; ++c) v += p[(size_t)c * 64 * N];
    if (bias) v += bias[n];
    if (res) v += res[(size_t)m * N + n];
    if (relu) v = fmaxf(v, 0.f);
    if (out1) out1[(size_t)m * N + n] = v;
    buf[n] = v; s += v;
  }
  red[tid] = s; __syncthreads();
  for (int st = 128; st > 0; st >>= 1) { if (tid < st) red[tid] += red[tid + st]; __syncthreads(); }
  const float mean = red[0] / N;
  __syncthreads();
  float vs = 0.f;
  for (int n = tid; n < N; n += 256) { float d = buf[n] - mean; vs += d * d; }
  red[tid] = vs; __syncthreads();
  for (int st = 128; st > 0; st >>= 1) { if (tid < st) red[tid] += red[tid + st]; __syncthreads(); }
  const float inv = rsqrtf(red[0] / N + 1e-5f);
  for (int n = tid; n < N; n += 256)
    out2[(size_t)m * N + n] = (buf[n] - mean) * inv * g[n] + b[n];
}

// ---- gemm32_nn: 64x32-tile split-K partial GEMM ----------------------------
__global__ __launch_bounds__(256) void gemm32_nn(
    const float* __restrict__ A, int lda, long sA,
    const float* __restrict__ B, int ldb, long sB,
    int N, int Kd, int nch,
    float* __restrict__ part, long pzs, int coff,
    int aCh, long aChS,
    const float* __restrict__ rsA, const float* __restrict__ bvA, long pzA) {
  __shared__ float As[64][64];
  __shared__ float Bs[64][40];
  const int tid = threadIdx.x;
  const int l16r = tid >> 4, l16c = tid & 15;
  const int lr = tid >> 3, lc = tid & 7;
  const int bn = blockIdx.x * 32;
  const int chunk = blockIdx.y;
  const int z = blockIdx.z;
  A += (long)z * sA; B += (long)z * sB;
  float acc[2][4] = {};
  const int ktiles = Kd >> 6;
  const int fa = (l16c & 7) << 2;
  for (int kt = chunk; kt < ktiles; kt += nch) {
    const int k0 = kt << 6;
    __syncthreads();
#pragma unroll
    for (int i = 0; i < 4; ++i) {
      const int r = l16r + 16 * i;
      float4 av;
      if (rsA) {
        const int kcol = k0 + l16c * 4;
        const int zz = kcol >> 7, d = kcol & 127;
        const float* ap = A + (size_t)zz * pzA + (size_t)r * 128 + d;
        av = *(const float4*)ap;
        for (int c = 1; c < aCh; ++c) {
          const float4 t2 = *(const float4*)(ap + (size_t)c * aChS);
          av.x += t2.x; av.y += t2.y; av.z += t2.z; av.w += t2.w;
        }
        const float4 bb = *(const float4*)(bvA + kcol);
        const float rv = rsA[zz * 64 + r];
        av.x += rv * bb.x; av.y += rv * bb.y; av.z += rv * bb.z; av.w += rv * bb.w;
      } else {
        const float* ap = A + (size_t)r * lda + k0 + l16c * 4;
        av = *(const float4*)ap;
        for (int c = 1; c < aCh; ++c) {
          const float4 t2 = *(const float4*)(ap + (size_t)c * aChS);
          av.x += t2.x; av.y += t2.y; av.z += t2.z; av.w += t2.w;
        }
      }
      As[l16c * 4 + 0][r ^ fa] = av.x; As[l16c * 4 + 1][r ^ fa] = av.y;
      As[l16c * 4 + 2][r ^ fa] = av.z; As[l16c * 4 + 3][r ^ fa] = av.w;
    }
#pragma unroll
    for (int i = 0; i < 2; ++i) {
      const int rb = lr + 32 * i;
      const float4 bv = *(const float4*)(B + (size_t)(k0 + rb) * ldb + bn + lc * 4);
      *(float4*)(&Bs[rb][lc * 4]) = bv;
    }
    __syncthreads();
#pragma unroll 8
    for (int kk = 0; kk < 64; ++kk) {
      const int fk = ((kk >> 2) & 7) << 2;
      const float2 a = *(const float2*)(&As[kk][(lr * 2) ^ fk]);
      const float4 b = *(const float4*)(&Bs[kk][lc * 4]);
      acc[0][0] += a.x * b.x; acc[0][1] += a.x * b.y; acc[0][2] += a.x * b.z; acc[0][3] += a.x * b.w;
      acc[1][0] += a.y * b.x; acc[1][1] += a.y * b.y; acc[1][2] += a.y * b.z; acc[1][3] += a.y * b.w;
    }
  }
  float* P = part + (size_t)z * pzs + (size_t)(coff + chunk) * 64 * N;
#pragma unroll
  for (int i = 0; i < 2; ++i) {
    const int m = lr * 2 + i;
#pragma unroll
    for (int j = 0; j < 4; ++j) P[(size_t)m * N + bn + lc * 4 + j] = acc[i][j];
  }
}

// ---------------- gemm_nn: C[64,N] = A[64,K] @ B[K,N] (vocab etc.) ----------
__global__ __launch_bounds__(256) void gemm_nn(
    const float* __restrict__ A, int lda, long sA,
    const float* __restrict__ B, int ldb, long sB,
    float* __restrict__ C, int ldc, long sC,
    const float* __restrict__ bias,
    const float* __restrict__ res, int ldres,
    int N, int Kd, int flags, int nch,
    float* __restrict__ part, long pzs, int coff,
    int aCh, long aChS) {
  __shared__ float As[64][64];
  __shared__ float Bs[64][64];
  const int tid = threadIdx.x;
  const int lr = tid >> 4, lc = tid & 15;
  const int bn = blockIdx.x * 64;
  const int chunk = blockIdx.y;
  const int z = blockIdx.z;
  A += (long)z * sA; B += (long)z * sB; C += (long)z * sC;
  float acc[4][4] = {};
  const int ktiles = Kd >> 6;
  const int fa = (lc & 7) << 2;
  for (int kt = chunk; kt < ktiles; kt += nch) {
    const int k0 = kt << 6;
    __syncthreads();
#pragma unroll
    for (int i = 0; i < 4; ++i) {
      const int r = lr + 16 * i;
      const float* ap = A + (size_t)r * lda + k0 + lc * 4;
      float4 av = *(const float4*)ap;
      for (int c = 1; c < aCh; ++c) {
        const float4 t2 = *(const float4*)(ap + (size_t)c * aChS);
        av.x += t2.x; av.y += t2.y; av.z += t2.z; av.w += t2.w;
      }
      As[lc * 4 + 0][r ^ fa] = av.x; As[lc * 4 + 1][r ^ fa] = av.y;
      As[lc * 4 + 2][r ^ fa] = av.z; As[lc * 4 + 3][r ^ fa] = av.w;
      const int n = bn + lc * 4;
      const float* bp = B + (size_t)(k0 + r) * ldb + n;
      float4 bv;
      if (n + 3 < N) bv = *(const float4*)bp;
      else {
        bv.x = (n + 0 < N) ? bp[0] : 0.f;
        bv.y = (n + 1 < N) ? bp[1] : 0.f;
        bv.z = (n + 2 < N) ? bp[2] : 0.f;
        bv.w = (n + 3 < N) ? bp[3] : 0.f;
      }
      *(float4*)(&Bs[r][SWZ(r, lc * 4)]) = bv;
    }
    __syncthreads();
#pragma unroll 8
    for (int kk = 0; kk < 64; ++kk) {
      const int fk = ((kk >> 2) & 7) << 2;
      const float4 a = *(const float4*)(&As[kk][(lr * 4) ^ fk]);
      const float4 b = *(const float4*)(&Bs[kk][(lc * 4) ^ fk]);
      acc[0][0] += a.x * b.x; acc[0][1] += a.x * b.y; acc[0][2] += a.x * b.z; acc[0][3] += a.x * b.w;
      acc[1][0] += a.y * b.x; acc[1][1] += a.y * b.y; acc[1][2] += a.y * b.z; acc[1][3] += a.y * b.w;
      acc[2][0] += a.z * b.x; acc[2][1] += a.z * b.y; acc[2][2] += a.z * b.z; acc[2][3] += a.z * b.w;
      acc[3][0] += a.w * b.x; acc[3][1] += a.w * b.y; acc[3][2] += a.w * b.z; acc[3][3] += a.w * b.w;
    }
  }
  if (part) {
    float* P = part + (size_t)z * pzs + (size_t)(coff + chunk) * 64 * N;
#pragma unroll
    for (int i = 0; i < 4; ++i) {
      const int m = lr * 4 + i;
#pragma unroll
      for (int j = 0; j < 4; ++j) {
        const int n = bn + lc * 4 + j;
        if (n < N) P[(size_t)m * N + n] = acc[i][j];
      }
    }
    return;
  }
#pragma unroll
  for (int i = 0; i < 4; ++i) {
    const int m = lr * 4 + i;
#pragma unroll
    for (int j = 0; j < 4; ++j) {
      const int n = bn + lc * 4 + j;
      if (n < N) {
        float v = acc[i][j];
        if (bias) v += bias[n];
        if (res) v += res[(size_t)m * ldres + n];
        if (flags & 2) v += C[(size_t)m * ldc + n];
        if (flags & 1) v = fmaxf(v, 0.f);
        C[(size_t)m * ldc + n] = v;
      }
    }
  }
}

// ---- gemm_nt: C[64,N] = A[64,K] @ B^T, splitK nch (chunk0->C, c>=1->part) --
__global__ __launch_bounds__(256) void gemm_nt(
    const float* __restrict__ A, int lda, long sA,
    const float* __restrict__ B, int ldb, long sB,
    float* __restrict__ C, int ldc, long sC,
    int N, int Kd, int nch, float* __restrict__ part) {
  __shared__ float As[64][64];
  __shared__ float Bs[64][64];
  const int tid = threadIdx.x;
  const int lr = tid >> 4, lc = tid & 15;
  const int bn = blockIdx.x * 64;
  const int chunk = blockIdx.y;
  const int z = blockIdx.z;
  A += (long)z * sA; B += (long)z * sB; C += (long)z * sC;
  float acc[4][4] = {};
  const int ktiles = Kd >> 6;
  const int fa = (lc & 7) << 2;
  for (int kt = chunk; kt < ktiles; kt += nch) {
    const int k0 = kt << 6;
    __syncthreads();
#pragma unroll
    for (int i = 0; i < 4; ++i) {
      const int r = lr + 16 * i;
      const float4 av = *(const float4*)(A + (size_t)r * lda + k0 + lc * 4);
      As[lc * 4 + 0][r ^ fa] = av.x; As[lc * 4 + 1][r ^ fa] = av.y;
      As[lc * 4 + 2][r ^ fa] = av.z; As[lc * 4 + 3][r ^ fa] = av.w;
      const float4 bv = *(const float4*)(B + (size_t)(bn + r) * ldb + k0 + lc * 4);
      Bs[lc * 4 + 0][r ^ fa] = bv.x; Bs[lc * 4 + 1][r ^ fa] = bv.y;
      Bs[lc * 4 + 2][r ^ fa] = bv.z; Bs[lc * 4 + 3][r ^ fa] = bv.w;
    }
    __syncthreads();
#pragma unroll 8
    for (int kk = 0; kk < 64; ++kk) {
      const int fk = ((kk >> 2) & 7) << 2;
      const float4 a = *(const float4*)(&As[kk][(lr * 4) ^ fk]);
      const float4 b = *(const float4*)(&Bs[kk][(lc * 4) ^ fk]);
      acc[0][0] += a.x * b.x; acc[0][1] += a.x * b.y; acc[0][2] += a.x * b.z; acc[0][3] += a.x * b.w;
      acc[1][0] += a.y * b.x; acc[1][1] += a.y * b.y; acc[1][2] += a.y * b.z; acc[1][3] += a.y * b.w;
      acc[2][0] += a.z * b.x; acc[2][1] += a.z * b.y; acc[2][2] += a.z * b.z; acc[2][3] += a.z * b.w;
      acc[3][0] += a.w * b.x; acc[3][1] += a.w * b.y; acc[3][2] += a.w * b.z; acc[3][3] += a.w * b.w;
    }
  }
  if (chunk == 0) {
#pragma unroll
    for (int i = 0; i < 4; ++i)
#pragma unroll
      for (int j = 0; j < 4; ++j)
        C[(size_t)(lr * 4 + i) * ldc + bn + lc * 4 + j] = acc[i][j];
  } else {
    float* P = part + (size_t)z * (64L * SEQ) + (size_t)(chunk - 1) * 64 * SEQ * NHD;
#pragma unroll
    for (int i = 0; i < 4; ++i)
#pragma unroll
      for (int j = 0; j < 4; ++j)
        P[(size_t)(lr * 4 + i) * SEQ + bn + lc * 4 + j] = acc[i][j];
  }
}

// ---- merged: qp (NT vs Wk) + scores-old (NN vs kcache) ---------------------
__global__ __launch_bounds__(256) void attn1_k(
    const float* __restrict__ qpart, const float* __restrict__ qbi_l,
    const float* __restrict__ Wkv, const float* __restrict__ kcl,
    float* __restrict__ qp, float* __restrict__ sc,
    int ckv, int sct) {
  __shared__ float As[64][64];
  __shared__ float Bs[64][64];
  const int tid = threadIdx.x;
  const int lr = tid >> 4, lc = tid & 15;
  const int h = blockIdx.z;
  const bool isQp = blockIdx.x < 8;
  const int bn = (isQp ? blockIdx.x : blockIdx.x - 8) * 64;
  const int fa = (lc & 7) << 2;
  float acc[4][4] = {};
  for (int k0 = 0; k0 < DKH; k0 += 64) {
    __syncthreads();
#pragma unroll
    for (int i = 0; i < 4; ++i) {
      const int r = lr + 16 * i;
      const float* ap = qpart + (size_t)r * HID + h * DKH + k0 + lc * 4;
      float4 av = *(const float4*)ap;
      for (int c = 1; c < 8; ++c) {
        const float4 t2 = *(const float4*)(ap + (size_t)c * 64 * HID);
        av.x += t2.x; av.y += t2.y; av.z += t2.z; av.w += t2.w;
      }
      const float4 bb = *(const float4*)(qbi_l + h * DKH + k0 + lc * 4);
      av.x += bb.x; av.y += bb.y; av.z += bb.z; av.w += bb.w;
      As[lc * 4 + 0][r ^ fa] = av.x; As[lc * 4 + 1][r ^ fa] = av.y;
      As[lc * 4 + 2][r ^ fa] = av.z; As[lc * 4 + 3][r ^ fa] = av.w;
      if (isQp) {
        const float4 bv = *(const float4*)(Wkv + (size_t)(bn + r) * (2 * HID) + h * DKH + k0 + lc * 4);
        Bs[lc * 4 + 0][r ^ fa] = bv.x; Bs[lc * 4 + 1][r ^ fa] = bv.y;
        Bs[lc * 4 + 2][r ^ fa] = bv.z; Bs[lc * 4 + 3][r ^ fa] = bv.w;
      } else {
        const float4 bv = *(const float4*)(kcl + ((size_t)h * DKH + k0 + r) * ckv + bn + lc * 4);
        *(float4*)(&Bs[r][SWZ(r, lc * 4)]) = bv;
      }
    }
    __syncthreads();
#pragma unroll 8
    for (int kk = 0; kk < 64; ++kk) {
      const int fk = ((kk >> 2) & 7) << 2;
      const float4 a = *(const float4*)(&As[kk][(lr * 4) ^ fk]);
      const float4 b = *(const float4*)(&Bs[kk][(lc * 4) ^ fk]);
      acc[0][0] += a.x * b.x; acc[0][1] += a.x * b.y; acc[0][2] += a.x * b.z; acc[0][3] += a.x * b.w;
      acc[1][0] += a.y * b.x; acc[1][1] += a.y * b.y; acc[1][2] += a.y * b.z; acc[1][3] += a.y * b.w;
      acc[2][0] += a.z * b.x; acc[2][1] += a.z * b.y; acc[2][2] += a.z * b.z; acc[2][3] += a.z * b.w;
      acc[3][0] += a.w * b.x; acc[3][1] += a.w * b.y; acc[3][2] += a.w * b.z; acc[3][3] += a.w * b.w;
    }
  }
  if (isQp) {
    float* C = qp + (size_t)h * TT * HID;
#pragma unroll
    for (int i = 0; i < 4; ++i)
#pragma unroll
      for (int j = 0; j < 4; ++j)
        C[(size_t)(lr * 4 + i) * HID + bn + lc * 4 + j] = acc[i][j];
  } else {
    float* C = sc + (size_t)h * TT * sct;
#pragma unroll
    for (int i = 0; i < 4; ++i)
#pragma unroll
      for (int j = 0; j < 4; ++j)
        C[(size_t)(lr * 4 + i) * sct + bn + lc * 4 + j] = acc[i][j];
  }
}

// ---- merged ctx partials: ctx-old (split ncho) + ctxE (split 8) ------------
__global__ __launch_bounds__(256) void attn2_k(
    const float* __restrict__ sc, const float* __restrict__ vcl,
    const float* __restrict__ enc,
    float* __restrict__ part, float* __restrict__ partE,
    int ckv, int sct, int ncho, long pzc) {
  __shared__ float As[64][64];
  __shared__ float Bs[64][64];
  const int tid = threadIdx.x;
  const int lr = tid >> 4, lc = tid & 15;
  const int h = blockIdx.z;
  const int by = blockIdx.y;
  const bool isOld = blockIdx.x < 2;
  if (isOld && by >= ncho) return;
  if (!isOld && by >= 8) return;
  const float* A;
  const float* Bb;
  int lda, ldb, N, ktiles, nch, bn;
  float* P;
  if (isOld) {
    A = sc + (size_t)h * TT * sct;  lda = sct;
    Bb = vcl + (size_t)h * ckv * DKH; ldb = DKH;
    N = DKH; ktiles = ckv >> 6; nch = ncho; bn = blockIdx.x * 64;
    P = part + (size_t)h * pzc + (size_t)by * 64 * DKH;
  } else {
    A = sc + ckv + (size_t)h * TT * sct; lda = sct;
    Bb = enc; ldb = HID;
    N = HID; ktiles = SEQ >> 6; nch = 8; bn = (blockIdx.x - 2) * 64;
    P = partE + (size_t)h * (8L * 64 * HID) + (size_t)by * 64 * HID;
  }
  const int fa = (lc & 7) << 2;
  float acc[4][4] = {};
  for (int kt = by; kt < ktiles; kt += nch) {
    const int k0 = kt << 6;
    __syncthreads();
#pragma unroll
    for (int i = 0; i < 4; ++i) {
      const int r = lr + 16 * i;
      const float4 av = *(const float4*)(A + (size_t)r * lda + k0 + lc * 4);
      As[lc * 4 + 0][r ^ fa] = av.x; As[lc * 4 + 1][r ^ fa] = av.y;
      As[lc * 4 + 2][r ^ fa] = av.z; As[lc * 4 + 3][r ^ fa] = av.w;
      const float4 bv = *(const float4*)(Bb + (size_t)(k0 + r) * ldb + bn + lc * 4);
      *(float4*)(&Bs[r][SWZ(r, lc * 4)]) = bv;
    }
    __syncthreads();
#pragma unroll 8
    for (int kk = 0; kk < 64; ++kk) {
      const int fk = ((kk >> 2) & 7) << 2;
      const float4 a = *(const float4*)(&As[kk][(lr * 4) ^ fk]);
      const float4 b = *(const float4*)(&Bs[kk][(lc * 4) ^ fk]);
      acc[0][0] += a.x * b.x; acc[0][1] += a.x * b.y; acc[0][2] += a.x * b.z; acc[0][3] += a.x * b.w;
      acc[1][0] += a.y * b.x; acc[1][1] += a.y * b.y; acc[1][2] += a.y * b.z; acc[1][3] += a.y * b.w;
      acc[2][0] += a.z * b.x; acc[2][1] += a.z * b.y; acc[2][2] += a.z * b.z; acc[2][3] += a.z * b.w;
      acc[3][0] += a.w * b.x; acc[3][1] += a.w * b.y; acc[3][2] += a.w * b.z; acc[3][3] += a.w * b.w;
    }
  }
#pragma unroll
  for (int i = 0; i < 4; ++i)
#pragma unroll
    for (int j = 0; j < 4; ++j)
      P[(size_t)(lr * 4 + i) * N + bn + lc * 4 + j] = acc[i][j];
}

// ---- fused FSMN conv + residuals + x_cat + LN3 (one block per row t) -------
__global__ __launch_bounds__(256) void fsmnln_k(
    const float* __restrict__ y4, const float* __restrict__ lfin,
    const float* __restrict__ cache, const float* __restrict__ fw,
    const float* __restrict__ g, const float* __restrict__ b,
    float* __restrict__ xb, float* __restrict__ xcat,
    float* __restrict__ y1out) {
  __shared__ float buf[HID];
  __shared__ float red[256];
  const int t = blockIdx.x, tid = threadIdx.x;
  float s = 0.f;
  for (int h = tid; h < HID; h += 256) {
    float conv = 0.f;
#pragma unroll
    for (int k = 0; k < KW; ++k) {
      const int j = t + k;
      const float xcv = (j < KW - 1) ? cache[h * (KW - 1) + j]
                                     : y4[(size_t)(j - (KW - 1)) * HID + h];
      conv += xcv * fw[h * KW + k];
    }
    const float yv = y4[(size_t)t * HID + h];
    const float x = conv + yv + lfin[(size_t)t * HID + h];
    xb[(size_t)t * HID + h] = x;
    buf[h] = x; s += x;
    xcat[h * (KW - 1 + TT) + (KW - 1) + t] = yv;
    if (t == 0) {
      for (int j2 = 0; j2 < KW - 1; ++j2)
        xcat[h * (KW - 1 + TT) + j2] = cache[h * (KW - 1) + j2];
    }
  }
  red[tid] = s; __syncthreads();
  for (int st = 128; st > 0; st >>= 1) { if (tid < st) red[tid] += red[tid + st]; __syncthreads(); }
  const float mean = red[0] / HID;
  __syncthreads();
  float vs = 0.f;
  for (int h = tid; h < HID; h += 256) { float d = buf[h] - mean; vs += d * d; }
  red[tid] = vs; __syncthreads();
  for (int st = 128; st > 0; st >>= 1) { if (tid < st) red[tid] += red[tid + st]; __syncthreads(); }
  const float inv = rsqrtf(red[0] / HID + 1e-5f);
  for (int h = tid; h < HID; h += 256)
    y1out[(size_t)t * HID + h] = (buf[h] - mean) * inv * g[h] + b[h];
}

// ---- single-pass LDS row softmax; fused qc-dot + scores-new partial sum ----
__global__ __launch_bounds__(256) void softmax_k(
    float* __restrict__ sc, float* __restrict__ rs,
    const float* __restrict__ qpart, const float* __restrict__ qbi_l,
    const float* __restrict__ kb, const float* __restrict__ partN,
    int cols, int newStart, float alpha) {
  __shared__ float srow[8192];
  __shared__ float red[256];
  const int tid = threadIdx.x;
  const int row = blockIdx.x;
  const int h = row >> 6, t = row & 63;
  sc += (size_t)row * cols;
  const float* pn = partN + (size_t)h * 64 * SEQ + (size_t)t * SEQ;
  float qv = 0.f;
  if (tid < DKH) {
    const float* qp0 = qpart + (size_t)t * HID + h * DKH + tid;
    float q = qp0[0];
    for (int c = 1; c < 8; ++c) q += qp0[(size_t)c * 64 * HID];
    q += qbi_l[h * DKH + tid];
    qv = q * kb[h * DKH + tid];
  }
  red[tid] = qv; __syncthreads();
  for (int st = 64; st > 0; st >>= 1) { if (tid < st) red[tid] += red[tid + st]; __syncthreads(); }
  const float qcv = red[0];
  __syncthreads();
  float m = -3.4e38f;
  for (int c = tid; c < cols; c += 256) {
    float v = sc[c];
    if (c >= newStart) v += pn[c - newStart] + qcv;
    v *= alpha;
    srow[c] = v; m = fmaxf(m, v);
  }
  red[tid] = m; __syncthreads();
  for (int st = 128; st > 0; st >>= 1) { if (tid < st) red[tid] = fmaxf(red[tid], red[tid + st]); __syncthreads(); }
  m = red[0]; __syncthreads();
  float s = 0.f;
  for (int c = tid; c < cols; c += 256) {
    const float e = __expf(srow[c] - m);
    srow[c] = e; s += e;
  }
  red[tid] = s; __syncthreads();
  for (int st = 128; st > 0; st >>= 1) { if (tid < st) red[tid] += red[tid + st]; __syncthreads(); }
  const float inv = 1.f / red[0];
  float ns = 0.f;
  for (int c = tid; c < cols; c += 256) {
    const float p = srow[c] * inv; sc[c] = p;
    if (c >= newStart) ns += p;
  }
  __syncthreads();
  red[tid] = ns; __syncthreads();
  for (int st = 128; st > 0; st >>= 1) { if (tid < st) red[tid] += red[tid + st]; __syncthreads(); }
  if (tid == 0) rs[row] = red[0];
}

// ---- Argmax over vocab: lg = P0 + P1 + bias (vocab splitK2 fold) -----------
__global__ __launch_bounds__(256) void argmax_k(const float* __restrict__ P0,
                                                const float* __restrict__ P1,
                                                const float* __restrict__ bias,
                                                float* __restrict__ out) {
  __shared__ float vs[256];
  __shared__ int ix[256];
  const int tid = threadIdx.x;
  P0 += (size_t)blockIdx.x * VOC;
  P1 += (size_t)blockIdx.x * VOC;
  float bm = -3.4e38f;
  int bi = 0;
  for (int c = tid; c < VOC; c += 256) {
    const float v = P0[c] + P1[c] + bias[c];
    if (v > bm) { bm = v; bi = c; }
  }
  vs[tid] = bm; ix[tid] = bi; __syncthreads();
  for (int st = 128; st > 0; st >>= 1) {
    if (tid < st) {
      if (vs[tid + st] > vs[tid] || (vs[tid + st] == vs[tid] && ix[tid + st] < ix[tid])) {
        vs[tid] = vs[tid + st]; ix[tid] = ix[tid + st];
      }
    }
    __syncthreads();
  }
  if (tid == 0) out[blockIdx.x] = (float)ix[0];
}

// ---------------- save_keys / save_values (runs on side stream) -------------
__global__ __launch_bounds__(256) void kvsave_k(const float* __restrict__ enc,
                                                const float* __restrict__ kvw,
                                                const float* __restrict__ kvb,
                                                float* __restrict__ keys,
                                                float* __restrict__ vals) {
  __shared__ float As[64][64];
  __shared__ float Bs[64][64];
  const int tid = threadIdx.x;
  const int lr = tid >> 4, lc = tid & 15;
  const int bn = blockIdx.x * 64, bm = blockIdx.y * 64;
  const int l = blockIdx.z;
  const float* W = kvw + (size_t)l * HID * 2 * HID;
  const int fa = (lc & 7) << 2;
  float acc[4][4] = {};
  for (int k0 = 0; k0 < HID; k0 += 64) {
    __syncthreads();
#pragma unroll
    for (int i = 0; i < 4; ++i) {
      const int r = lr + 16 * i;
      const float4 av =
          *(const float4*)(enc + (size_t)(SEQ - LBN + bm + r) * HID + k0 + lc * 4);
      As[lc * 4 + 0][r ^ fa] = av.x; As[lc * 4 + 1][r ^ fa] = av.y;
      As[lc * 4 + 2][r ^ fa] = av.z; As[lc * 4 + 3][r ^ fa] = av.w;
      const float4 bv = *(const float4*)(W + (size_t)(k0 + r) * (2 * HID) + bn + lc * 4);
      *(float4*)(&Bs[r][SWZ(r, lc * 4)]) = bv;
    }
    __syncthreads();
#pragma unroll 8
    for (int kk = 0; kk < 64; ++kk) {
      const int fk = ((kk >> 2) & 7) << 2;
      const float4 a = *(const float4*)(&As[kk][(lr * 4) ^ fk]);
      const float4 b = *(const float4*)(&Bs[kk][(lc * 4) ^ fk]);
      acc[0][0] += a.x * b.x; acc[0][1] += a.x * b.y; acc[0][2] += a.x * b.z; acc[0][3] += a.x * b.w;
      acc[1][0] += a.y * b.x; acc[1][1] += a.y * b.y; acc[1][2] += a.y * b.z; acc[1][3] += a.y * b.w;
      acc[2][0] += a.z * b.x; acc[2][1] += a.z * b.y; acc[2][2] += a.z * b.z; acc[2][3] += a.z * b.w;
      acc[3][0] += a.w * b.x; acc[3][1] += a.w * b.y; acc[3][2] += a.w * b.z; acc[3][3] += a.w * b.w;
    }
  }
#pragma unroll
  for (int i = 0; i < 4; ++i) {
    const int m = bm + lr * 4 + i;
#pragma unroll
    for (int j = 0; j < 4; ++j) {
      const int n = bn + lc * 4 + j;
      const float v = acc[i][j] + kvb[(size_t)l * 2 * HID + n];
      if (n < 512) {
        const int h = n >> 7, d = n & 127;
        keys[(((size_t)l * NHD + h) * DKH + d) * LBN + m] = v;
      } else {
        const int c = n - 512, h = c >> 7, d = c & 127;
        vals[(((size_t)l * NHD + h) * LBN + m) * DKH + d] = v;
      }
    }
  }
}

extern "C" void kernel_launch(void* const* d_in, const int* in_sizes, int n_in,
                              void* d_out, int out_size, void* d_ws, size_t ws_size,
                              hipStream_t stream) {
  static const int EXPECT[34] = {
      1048576, 32768, 81920, -1, -1,
      8192, 8192, 8192, 8192, 8192, 8192,
      32768, 32768,
      16777216, 32768, 16777216, 90112,
      4194304, 8192, 8388608, 16384, 4194304, 8192,
      512, 512, 1048576, 2048, 2048, 2048, 1048576,
      512, 512, 4302848, 8404};
  if (out_size != 4800576) {
    diag_k<<<1, 64, 0, stream>>>((float*)d_out, 9800000.f);
    return;
  }
  float* out_fsmn = (float*)d_out;
  float* out_keys = out_fsmn + (size_t)LAY * HID * (KW - 1 + TT);
  float* out_vals = out_keys + (size_t)LAY * NHD * DKH * LBN;
  float* out_ids  = out_vals + (size_t)LAY * NHD * LBN * DKH;
  if (n_in < 34) {
    diag_k<<<1, 64, 0, stream>>>(out_ids, 9900000.f);
    return;
  }
  for (int i = 0; i < 34; ++i) {
    if (EXPECT[i] >= 0 && in_sizes[i] != EXPECT[i]) {
      diag_k<<<1, 64, 0, stream>>>(out_ids, (float)((i + 1) * 100000));
      return;
    }
  }
  const long per = (long)LAY * NHD * DKH;
  const long ckl = (long)in_sizes[3] / per;
  if ((long)in_sizes[3] != ckl * per || in_sizes[4] != in_sizes[3] ||
      ckl <= 0 || (ckl & 63) != 0 || ckl > 6144) {
    diag_k<<<1, 64, 0, stream>>>(out_fsmn, (float)in_sizes[3]);
    return;
  }
  // scratch fully in d_ws now (needs ~24.4 MB); r12 proved ws >= 33.5 MB
  if (ws_size < (size_t)8388608 * 4) {
    diag_k<<<1, 64, 0, stream>>>(out_fsmn, 1.0e6f + (float)(ws_size >> 20));
    return;
  }
  const int ckv = (int)ckl;
  const int sct = ckv + SEQ;
  const long TS = (long)TT * sct;
  const int ncho = (ckv / 64 < 8) ? (ckv / 64) : 8;

  const float* enc    = (const float*)d_in[0];
  const float* lfrm   = (const float*)d_in[1];
  const float* fcache = (const float*)d_in[2];
  const float* kcache = (const float*)d_in[3];
  const float* vcache = (const float*)d_in[4];
  const float* n1g = (const float*)d_in[5];  const float* n1b = (const float*)d_in[6];
  const float* n2g = (const float*)d_in[7];  const float* n2b = (const float*)d_in[8];
  const float* n3g = (const float*)d_in[9];  const float* n3b = (const float*)d_in[10];
  const float* fng = (const float*)d_in[11]; const float* fnb = (const float*)d_in[12];
  const float* w1  = (const float*)d_in[13]; const float* b1  = (const float*)d_in[14];
  const float* w2  = (const float*)d_in[15];
  const float* fw  = (const float*)d_in[16];
  const float* qw  = (const float*)d_in[17]; const float* qbi  = (const float*)d_in[18];
  const float* kvw = (const float*)d_in[19]; const float* kvbi = (const float*)d_in[20];
  const float* ow  = (const float*)d_in[21]; const float* obi  = (const float*)d_in[22];
  const float* d3n1g = (const float*)d_in[23]; const float* d3n1b = (const float*)d_in[24];
  const float* d3w1  = (const float*)d_in[25]; const float* d3b1  = (const float*)d_in[26];
  const float* d3fng = (const float*)d_in[27]; const float* d3fnb = (const float*)d_in[28];
  const float* d3w2  = (const float*)d_in[29];
  const float* ang   = (const float*)d_in[30]; const float* anb = (const float*)d_in[31];
  const float* outw  = (const float*)d_in[32]; const float* outb = (const float*)d_in[33];

  // d_ws layout (floats): partials + vocab partials + all chain scratch
  float* wsf   = (float*)d_ws;
  float* part  = wsf;                 // 524288
  float* part2 = wsf + 524288;        // 524288
  float* partE = wsf + 1048576;       // 1048576
  float* partN = wsf + 2097152;       // 524288
  float* vp    = wsf + 2621440;       // 2*64*VOC = 1075712
  float* sb    = wsf + 3697152;       // chain scratch base
  float* lf  = sb + 0;                // 32768
  float* y1  = sb + 32768;            // 32768
  float* y4  = sb + 65536;            // 32768
  float* xb  = sb + 98304;            // 32768
  float* y2  = sb + 131072;           // 32768
  float* qp  = sb + 163840;           // 131072
  float* rs  = sb + 294912;           // 256
  float* sc  = sb + 295168;           // 256*sct <= 2097152 (total <= 6089472)

  const float alpha = 0.08838834764831845f;
  const long TH = (long)TT * HID;
  const long pz_ctx = (long)(ncho + 4) * 64 * DKH;

  // ---- first node (single graph root) ----
  redln_k<<<TT, 256, 0, stream>>>(lfrm, HID, 1, nullptr, nullptr, 0,
                                  n1g, n1b, lf, y1);

  // ---- fork side stream AFTER the root node; kvsave overlaps the chain ----
  hipStream_t s2;
  hipStreamCreateWithFlags(&s2, hipStreamNonBlocking);
  hipEvent_t evFork, evKv;
  hipEventCreateWithFlags(&evFork, hipEventDisableTiming);
  hipEventCreateWithFlags(&evKv, hipEventDisableTiming);
  hipEventRecord(evFork, stream);
  hipStreamWaitEvent(s2, evFork, 0);
  kvsave_k<<<dim3(2 * HID / 64, LBN / 64, LAY), 256, 0, s2>>>(
      enc, kvw, kvbi, out_keys, out_vals);
  hipEventRecord(evKv, s2);

  for (int l = 0; l < LAY; ++l) {
    const float* Wkv = kvw + (size_t)l * HID * 2 * HID;
    const float* Bkv = kvbi + (size_t)l * 2 * HID;
    const float* qbi_l = qbi + (size_t)l * HID;
    gemm32_nn<<<dim3(64, 8, 1), 256, 0, stream>>>(
        y1, HID, 0, w1 + (size_t)l * HID * FF, FF, 0, FF, HID, 8, part2, 0, 0,
        1, 0, nullptr, nullptr, 0);
    redln_k<<<TT, 256, 0, stream>>>(part2, FF, 8, b1 + (size_t)l * FF, nullptr, 1,
                                    fng + (size_t)l * FF, fnb + (size_t)l * FF,
                                    nullptr, y2);
    gemm32_nn<<<dim3(16, 32, 1), 256, 0, stream>>>(
        y2, FF, 0, w2 + (size_t)l * FF * HID, HID, 0, HID, FF, 32, part2, 0, 0,
        1, 0, nullptr, nullptr, 0);
    redln_k<<<TT, 256, 0, stream>>>(part2, HID, 32, nullptr, nullptr, 0,
                                    n2g + l * HID, n2b + l * HID, nullptr, y4);
    fsmnln_k<<<TT, 256, 0, stream>>>(y4, lf, fcache + (size_t)l * HID * (KW - 1),
                                     fw + (size_t)l * HID * KW,
                                     n3g + l * HID, n3b + l * HID,
                                     xb, out_fsmn + (size_t)l * HID * (KW - 1 + TT), y1);
    gemm32_nn<<<dim3(16, 8, 1), 256, 0, stream>>>(
        y1, HID, 0, qw + (size_t)l * HID * HID, HID, 0, HID, HID, 8, part2, 0, 0,
        1, 0, nullptr, nullptr, 0);
    attn1_k<<<dim3(8 + ckv / 64, 1, NHD), 256, 0, stream>>>(
        part2, qbi_l, Wkv, kcache + (size_t)l * NHD * DKH * ckv, qp, sc, ckv, sct);
    gemm_nt<<<dim3(32, 2, NHD), 256, 0, stream>>>(
        qp, HID, TH, enc, HID, 0, sc + ckv, sct, TS, SEQ, HID, 2, partN);
    softmax_k<<<NHD * TT, 256, 0, stream>>>(sc, rs, part2, qbi_l, Bkv, partN,
                                            sct, ckv, alpha);
    attn2_k<<<dim3(10, 8, NHD), 256, 0, stream>>>(
        sc, vcache + (size_t)l * NHD * ckv * DKH, enc, part, partE,
        ckv, sct, ncho, pz_ctx);
    gemm32_nn<<<dim3(4, 4, NHD), 256, 0, stream>>>(
        partE, HID, 8L * 64 * HID, Wkv + HID, 2 * HID, DKH, DKH, HID, 4,
        part, pz_ctx, ncho, 8, 64L * HID, nullptr, nullptr, 0);
    gemm32_nn<<<dim3(16, 8, 1), 256, 0, stream>>>(
        part, 0, 0, ow + (size_t)l * HID * HID, HID, 0, HID, HID, 8, part2, 0, 0,
        ncho + 4, 8192, rs, Bkv + HID, pz_ctx);
    const float* ng = (l + 1 < LAY) ? n1g + (l + 1) * HID : d3n1g;
    const float* nb = (l + 1 < LAY) ? n1b + (l + 1) * HID : d3n1b;
    redln_k<<<TT, 256, 0, stream>>>(part2, HID, 8, obi + (size_t)l * HID, xb, 0,
                                    ng, nb, lf, y1);
  }

  // ---- final decoder3 block + vocab (splitK2) + argmax (folds sum+bias) ----
  gemm32_nn<<<dim3(64, 8, 1), 256, 0, stream>>>(
      y1, HID, 0, d3w1, FF, 0, FF, HID, 8, part2, 0, 0, 1, 0, nullptr, nullptr, 0);
  redln_k<<<TT, 256, 0, stream>>>(part2, FF, 8, d3b1, nullptr, 1,
                                  d3fng, d3fnb, nullptr, y2);
  gemm32_nn<<<dim3(16, 32, 1), 256, 0, stream>>>(
      y2, FF, 0, d3w2, HID, 0, HID, FF, 32, part2, 0, 0, 1, 0, nullptr, nullptr, 0);
  redln_k<<<TT, 256, 0, stream>>>(part2, HID, 32, nullptr, nullptr, 0,
                                  ang, anb, nullptr, y4);
  gemm_nn<<<dim3((VOC + 63) / 64, 2, 1), 256, 0, stream>>>(
      y4, HID, 0, outw, VOC, 0, nullptr, 0, 0, nullptr, nullptr, 0,
      VOC, HID, 0, 2, vp, 0, 0, 1, 0);
  argmax_k<<<TT, 256, 0, stream>>>(vp, vp + 64L * VOC, outb, out_ids);

  // ---- join side stream before capture end ----
  hipStreamWaitEvent(stream, evKv, 0);
}

// Round 21
// 2871.052 us; speedup vs baseline: 1.0666x; 1.0666x over previous
//
#include <hip/hip_runtime.h>

// Paraformer-large streaming decoder dims (CKV derived at runtime from in_sizes)
constexpr int LAY = 16, HID = 512, FF = 2048, NHD = 4, DKH = 128, KW = 11,
              VOC = 8404, TT = 64, SEQ = 2048, LBN = 256;

// LDS XOR swizzle (proven r13): kills 8-way store conflicts
#define SWZ(row, e) ((e) ^ ((((row) >> 2) & 7) << 2))

// ---------------- diagnostic: write value to 64 floats ----------------
__global__ void diag_k(float* __restrict__ p, float v) { p[threadIdx.x] = v; }

// ---- fused split-K reduce + bias/res/relu + LayerNorm (one block per row) --
__global__ __launch_bounds__(256) void redln_k(
    const float* __restrict__ P, int N, int nch,
    const float* __restrict__ bias, const float* __restrict__ res, int relu,
    const float* __restrict__ g, const float* __restrict__ b,
    float* __restrict__ out1, float* __restrict__ out2) {
  __shared__ float buf[2048];
  __shared__ float red[256];
  const int m = blockIdx.x, tid = threadIdx.x;
  float s = 0.f;
  for (int n = tid; n < N; n += 256) {
    const float* p = P + (size_t)m * N + n;
    float v = 0.f;
    for (int c = 0; c < nch; ++c) v += p[(size_t)c * 64 * N];
    if (bias) v += bias[n];
    if (res) v += res[(size_t)m * N + n];
    if (relu) v = fmaxf(v, 0.f);
    if (out1) out1[(size_t)m * N + n] = v;
    buf[n] = v; s += v;
  }
  red[tid] = s; __syncthreads();
  for (int st = 128; st > 0; st >>= 1) { if (tid < st) red[tid] += red[tid + st]; __syncthreads(); }
  const float mean = red[0] / N;
  __syncthreads();
  float vs = 0.f;
  for (int n = tid; n < N; n += 256) { float d = buf[n] - mean; vs += d * d; }
  red[tid] = vs; __syncthreads();
  for (int st = 128; st > 0; st >>= 1) { if (tid < st) red[tid] += red[tid + st]; __syncthreads(); }
  const float inv = rsqrtf(red[0] / N + 1e-5f);
  for (int n = tid; n < N; n += 256)
    out2[(size_t)m * N + n] = (buf[n] - mean) * inv * g[n] + b[n];
}

// ---- gemm32_nn: 64x32-tile split-K partial GEMM ----------------------------
// Normal A mode: aCh chunks (stride aChS) summed on load.
// ctx mode (rsA != null): A element (r,k) = sum_{c<aCh} A[(k>>7)*pzA + c*8192
//   + r*128 + (k&127)] + rsA[(k>>7)*64 + r] * bvA[k]  (folds ctx reduce).
__global__ __launch_bounds__(256) void gemm32_nn(
    const float* __restrict__ A, int lda, long sA,
    const float* __restrict__ B, int ldb, long sB,
    int N, int Kd, int nch,
    float* __restrict__ part, long pzs, int coff,
    int aCh, long aChS,
    const float* __restrict__ rsA, const float* __restrict__ bvA, long pzA) {
  __shared__ float As[64][64];
  __shared__ float Bs[64][40];
  const int tid = threadIdx.x;
  const int l16r = tid >> 4, l16c = tid & 15;
  const int lr = tid >> 3, lc = tid & 7;
  const int bn = blockIdx.x * 32;
  const int chunk = blockIdx.y;
  const int z = blockIdx.z;
  A += (long)z * sA; B += (long)z * sB;
  float acc[2][4] = {};
  const int ktiles = Kd >> 6;
  const int fa = (l16c & 7) << 2;
  for (int kt = chunk; kt < ktiles; kt += nch) {
    const int k0 = kt << 6;
    __syncthreads();
#pragma unroll
    for (int i = 0; i < 4; ++i) {
      const int r = l16r + 16 * i;
      float4 av;
      if (rsA) {
        const int kcol = k0 + l16c * 4;
        const int zz = kcol >> 7, d = kcol & 127;
        const float* ap = A + (size_t)zz * pzA + (size_t)r * 128 + d;
        av = *(const float4*)ap;
        for (int c = 1; c < aCh; ++c) {
          const float4 t2 = *(const float4*)(ap + (size_t)c * aChS);
          av.x += t2.x; av.y += t2.y; av.z += t2.z; av.w += t2.w;
        }
        const float4 bb = *(const float4*)(bvA + kcol);
        const float rv = rsA[zz * 64 + r];
        av.x += rv * bb.x; av.y += rv * bb.y; av.z += rv * bb.z; av.w += rv * bb.w;
      } else {
        const float* ap = A + (size_t)r * lda + k0 + l16c * 4;
        av = *(const float4*)ap;
        for (int c = 1; c < aCh; ++c) {
          const float4 t2 = *(const float4*)(ap + (size_t)c * aChS);
          av.x += t2.x; av.y += t2.y; av.z += t2.z; av.w += t2.w;
        }
      }
      As[l16c * 4 + 0][r ^ fa] = av.x; As[l16c * 4 + 1][r ^ fa] = av.y;
      As[l16c * 4 + 2][r ^ fa] = av.z; As[l16c * 4 + 3][r ^ fa] = av.w;
    }
#pragma unroll
    for (int i = 0; i < 2; ++i) {
      const int rb = lr + 32 * i;
      const float4 bv = *(const float4*)(B + (size_t)(k0 + rb) * ldb + bn + lc * 4);
      *(float4*)(&Bs[rb][lc * 4]) = bv;
    }
    __syncthreads();
#pragma unroll 8
    for (int kk = 0; kk < 64; ++kk) {
      const int fk = ((kk >> 2) & 7) << 2;
      const float2 a = *(const float2*)(&As[kk][(lr * 2) ^ fk]);
      const float4 b = *(const float4*)(&Bs[kk][lc * 4]);
      acc[0][0] += a.x * b.x; acc[0][1] += a.x * b.y; acc[0][2] += a.x * b.z; acc[0][3] += a.x * b.w;
      acc[1][0] += a.y * b.x; acc[1][1] += a.y * b.y; acc[1][2] += a.y * b.z; acc[1][3] += a.y * b.w;
    }
  }
  float* P = part + (size_t)z * pzs + (size_t)(coff + chunk) * 64 * N;
#pragma unroll
  for (int i = 0; i < 2; ++i) {
    const int m = lr * 2 + i;
#pragma unroll
    for (int j = 0; j < 4; ++j) P[(size_t)m * N + bn + lc * 4 + j] = acc[i][j];
  }
}

// ---------------- gemm_nn: C[64,N] = A[64,K] @ B[K,N] (vocab etc.) ----------
__global__ __launch_bounds__(256) void gemm_nn(
    const float* __restrict__ A, int lda, long sA,
    const float* __restrict__ B, int ldb, long sB,
    float* __restrict__ C, int ldc, long sC,
    const float* __restrict__ bias,
    const float* __restrict__ res, int ldres,
    int N, int Kd, int flags, int nch,
    float* __restrict__ part, long pzs, int coff,
    int aCh, long aChS) {
  __shared__ float As[64][64];
  __shared__ float Bs[64][64];
  const int tid = threadIdx.x;
  const int lr = tid >> 4, lc = tid & 15;
  const int bn = blockIdx.x * 64;
  const int chunk = blockIdx.y;
  const int z = blockIdx.z;
  A += (long)z * sA; B += (long)z * sB; C += (long)z * sC;
  float acc[4][4] = {};
  const int ktiles = Kd >> 6;
  const int fa = (lc & 7) << 2;
  for (int kt = chunk; kt < ktiles; kt += nch) {
    const int k0 = kt << 6;
    __syncthreads();
#pragma unroll
    for (int i = 0; i < 4; ++i) {
      const int r = lr + 16 * i;
      const float* ap = A + (size_t)r * lda + k0 + lc * 4;
      float4 av = *(const float4*)ap;
      for (int c = 1; c < aCh; ++c) {
        const float4 t2 = *(const float4*)(ap + (size_t)c * aChS);
        av.x += t2.x; av.y += t2.y; av.z += t2.z; av.w += t2.w;
      }
      As[lc * 4 + 0][r ^ fa] = av.x; As[lc * 4 + 1][r ^ fa] = av.y;
      As[lc * 4 + 2][r ^ fa] = av.z; As[lc * 4 + 3][r ^ fa] = av.w;
      const int n = bn + lc * 4;
      const float* bp = B + (size_t)(k0 + r) * ldb + n;
      float4 bv;
      if (n + 3 < N) bv = *(const float4*)bp;
      else {
        bv.x = (n + 0 < N) ? bp[0] : 0.f;
        bv.y = (n + 1 < N) ? bp[1] : 0.f;
        bv.z = (n + 2 < N) ? bp[2] : 0.f;
        bv.w = (n + 3 < N) ? bp[3] : 0.f;
      }
      *(float4*)(&Bs[r][SWZ(r, lc * 4)]) = bv;
    }
    __syncthreads();
#pragma unroll 8
    for (int kk = 0; kk < 64; ++kk) {
      const int fk = ((kk >> 2) & 7) << 2;
      const float4 a = *(const float4*)(&As[kk][(lr * 4) ^ fk]);
      const float4 b = *(const float4*)(&Bs[kk][(lc * 4) ^ fk]);
      acc[0][0] += a.x * b.x; acc[0][1] += a.x * b.y; acc[0][2] += a.x * b.z; acc[0][3] += a.x * b.w;
      acc[1][0] += a.y * b.x; acc[1][1] += a.y * b.y; acc[1][2] += a.y * b.z; acc[1][3] += a.y * b.w;
      acc[2][0] += a.z * b.x; acc[2][1] += a.z * b.y; acc[2][2] += a.z * b.z; acc[2][3] += a.z * b.w;
      acc[3][0] += a.w * b.x; acc[3][1] += a.w * b.y; acc[3][2] += a.w * b.z; acc[3][3] += a.w * b.w;
    }
  }
  if (part) {
    float* P = part + (size_t)z * pzs + (size_t)(coff + chunk) * 64 * N;
#pragma unroll
    for (int i = 0; i < 4; ++i) {
      const int m = lr * 4 + i;
#pragma unroll
      for (int j = 0; j < 4; ++j) {
        const int n = bn + lc * 4 + j;
        if (n < N) P[(size_t)m * N + n] = acc[i][j];
      }
    }
    return;
  }
#pragma unroll
  for (int i = 0; i < 4; ++i) {
    const int m = lr * 4 + i;
#pragma unroll
    for (int j = 0; j < 4; ++j) {
      const int n = bn + lc * 4 + j;
      if (n < N) {
        float v = acc[i][j];
        if (bias) v += bias[n];
        if (res) v += res[(size_t)m * ldres + n];
        if (flags & 2) v += C[(size_t)m * ldc + n];
        if (flags & 1) v = fmaxf(v, 0.f);
        C[(size_t)m * ldc + n] = v;
      }
    }
  }
}

// ---- gemm_nt: C[64,N] = A[64,K] @ B^T, splitK nch (chunk0->C, c>=1->part) --
__global__ __launch_bounds__(256) void gemm_nt(
    const float* __restrict__ A, int lda, long sA,
    const float* __restrict__ B, int ldb, long sB,
    float* __restrict__ C, int ldc, long sC,
    int N, int Kd, int nch, float* __restrict__ part) {
  __shared__ float As[64][64];
  __shared__ float Bs[64][64];
  const int tid = threadIdx.x;
  const int lr = tid >> 4, lc = tid & 15;
  const int bn = blockIdx.x * 64;
  const int chunk = blockIdx.y;
  const int z = blockIdx.z;
  A += (long)z * sA; B += (long)z * sB; C += (long)z * sC;
  float acc[4][4] = {};
  const int ktiles = Kd >> 6;
  const int fa = (lc & 7) << 2;
  for (int kt = chunk; kt < ktiles; kt += nch) {
    const int k0 = kt << 6;
    __syncthreads();
#pragma unroll
    for (int i = 0; i < 4; ++i) {
      const int r = lr + 16 * i;
      const float4 av = *(const float4*)(A + (size_t)r * lda + k0 + lc * 4);
      As[lc * 4 + 0][r ^ fa] = av.x; As[lc * 4 + 1][r ^ fa] = av.y;
      As[lc * 4 + 2][r ^ fa] = av.z; As[lc * 4 + 3][r ^ fa] = av.w;
      const float4 bv = *(const float4*)(B + (size_t)(bn + r) * ldb + k0 + lc * 4);
      Bs[lc * 4 + 0][r ^ fa] = bv.x; Bs[lc * 4 + 1][r ^ fa] = bv.y;
      Bs[lc * 4 + 2][r ^ fa] = bv.z; Bs[lc * 4 + 3][r ^ fa] = bv.w;
    }
    __syncthreads();
#pragma unroll 8
    for (int kk = 0; kk < 64; ++kk) {
      const int fk = ((kk >> 2) & 7) << 2;
      const float4 a = *(const float4*)(&As[kk][(lr * 4) ^ fk]);
      const float4 b = *(const float4*)(&Bs[kk][(lc * 4) ^ fk]);
      acc[0][0] += a.x * b.x; acc[0][1] += a.x * b.y; acc[0][2] += a.x * b.z; acc[0][3] += a.x * b.w;
      acc[1][0] += a.y * b.x; acc[1][1] += a.y * b.y; acc[1][2] += a.y * b.z; acc[1][3] += a.y * b.w;
      acc[2][0] += a.z * b.x; acc[2][1] += a.z * b.y; acc[2][2] += a.z * b.z; acc[2][3] += a.z * b.w;
      acc[3][0] += a.w * b.x; acc[3][1] += a.w * b.y; acc[3][2] += a.w * b.z; acc[3][3] += a.w * b.w;
    }
  }
  if (chunk == 0) {
#pragma unroll
    for (int i = 0; i < 4; ++i)
#pragma unroll
      for (int j = 0; j < 4; ++j)
        C[(size_t)(lr * 4 + i) * ldc + bn + lc * 4 + j] = acc[i][j];
  } else {
    float* P = part + (size_t)z * (64L * SEQ) + (size_t)(chunk - 1) * 64 * SEQ * NHD;
#pragma unroll
    for (int i = 0; i < 4; ++i)
#pragma unroll
      for (int j = 0; j < 4; ++j)
        P[(size_t)(lr * 4 + i) * SEQ + bn + lc * 4 + j] = acc[i][j];
  }
}

// ---- merged: qp (NT vs Wk) + scores-old (NN vs kcache) ---------------------
__global__ __launch_bounds__(256) void attn1_k(
    const float* __restrict__ qpart, const float* __restrict__ qbi_l,
    const float* __restrict__ Wkv, const float* __restrict__ kcl,
    float* __restrict__ qp, float* __restrict__ sc,
    int ckv, int sct) {
  __shared__ float As[64][64];
  __shared__ float Bs[64][64];
  const int tid = threadIdx.x;
  const int lr = tid >> 4, lc = tid & 15;
  const int h = blockIdx.z;
  const bool isQp = blockIdx.x < 8;
  const int bn = (isQp ? blockIdx.x : blockIdx.x - 8) * 64;
  const int fa = (lc & 7) << 2;
  float acc[4][4] = {};
  for (int k0 = 0; k0 < DKH; k0 += 64) {
    __syncthreads();
#pragma unroll
    for (int i = 0; i < 4; ++i) {
      const int r = lr + 16 * i;
      const float* ap = qpart + (size_t)r * HID + h * DKH + k0 + lc * 4;
      float4 av = *(const float4*)ap;
      for (int c = 1; c < 8; ++c) {
        const float4 t2 = *(const float4*)(ap + (size_t)c * 64 * HID);
        av.x += t2.x; av.y += t2.y; av.z += t2.z; av.w += t2.w;
      }
      const float4 bb = *(const float4*)(qbi_l + h * DKH + k0 + lc * 4);
      av.x += bb.x; av.y += bb.y; av.z += bb.z; av.w += bb.w;
      As[lc * 4 + 0][r ^ fa] = av.x; As[lc * 4 + 1][r ^ fa] = av.y;
      As[lc * 4 + 2][r ^ fa] = av.z; As[lc * 4 + 3][r ^ fa] = av.w;
      if (isQp) {
        const float4 bv = *(const float4*)(Wkv + (size_t)(bn + r) * (2 * HID) + h * DKH + k0 + lc * 4);
        Bs[lc * 4 + 0][r ^ fa] = bv.x; Bs[lc * 4 + 1][r ^ fa] = bv.y;
        Bs[lc * 4 + 2][r ^ fa] = bv.z; Bs[lc * 4 + 3][r ^ fa] = bv.w;
      } else {
        const float4 bv = *(const float4*)(kcl + ((size_t)h * DKH + k0 + r) * ckv + bn + lc * 4);
        *(float4*)(&Bs[r][SWZ(r, lc * 4)]) = bv;
      }
    }
    __syncthreads();
#pragma unroll 8
    for (int kk = 0; kk < 64; ++kk) {
      const int fk = ((kk >> 2) & 7) << 2;
      const float4 a = *(const float4*)(&As[kk][(lr * 4) ^ fk]);
      const float4 b = *(const float4*)(&Bs[kk][(lc * 4) ^ fk]);
      acc[0][0] += a.x * b.x; acc[0][1] += a.x * b.y; acc[0][2] += a.x * b.z; acc[0][3] += a.x * b.w;
      acc[1][0] += a.y * b.x; acc[1][1] += a.y * b.y; acc[1][2] += a.y * b.z; acc[1][3] += a.y * b.w;
      acc[2][0] += a.z * b.x; acc[2][1] += a.z * b.y; acc[2][2] += a.z * b.z; acc[2][3] += a.z * b.w;
      acc[3][0] += a.w * b.x; acc[3][1] += a.w * b.y; acc[3][2] += a.w * b.z; acc[3][3] += a.w * b.w;
    }
  }
  if (isQp) {
    float* C = qp + (size_t)h * TT * HID;
#pragma unroll
    for (int i = 0; i < 4; ++i)
#pragma unroll
      for (int j = 0; j < 4; ++j)
        C[(size_t)(lr * 4 + i) * HID + bn + lc * 4 + j] = acc[i][j];
  } else {
    float* C = sc + (size_t)h * TT * sct;
#pragma unroll
    for (int i = 0; i < 4; ++i)
#pragma unroll
      for (int j = 0; j < 4; ++j)
        C[(size_t)(lr * 4 + i) * sct + bn + lc * 4 + j] = acc[i][j];
  }
}

// ---- merged ctx partials: ctx-old (split ncho) + ctxE (split 8) ------------
__global__ __launch_bounds__(256) void attn2_k(
    const float* __restrict__ sc, const float* __restrict__ vcl,
    const float* __restrict__ enc,
    float* __restrict__ part, float* __restrict__ partE,
    int ckv, int sct, int ncho, long pzc) {
  __shared__ float As[64][64];
  __shared__ float Bs[64][64];
  const int tid = threadIdx.x;
  const int lr = tid >> 4, lc = tid & 15;
  const int h = blockIdx.z;
  const int by = blockIdx.y;
  const bool isOld = blockIdx.x < 2;
  if (isOld && by >= ncho) return;
  if (!isOld && by >= 8) return;
  const float* A;
  const float* Bb;
  int lda, ldb, N, ktiles, nch, bn;
  float* P;
  if (isOld) {
    A = sc + (size_t)h * TT * sct;  lda = sct;
    Bb = vcl + (size_t)h * ckv * DKH; ldb = DKH;
    N = DKH; ktiles = ckv >> 6; nch = ncho; bn = blockIdx.x * 64;
    P = part + (size_t)h * pzc + (size_t)by * 64 * DKH;
  } else {
    A = sc + ckv + (size_t)h * TT * sct; lda = sct;
    Bb = enc; ldb = HID;
    N = HID; ktiles = SEQ >> 6; nch = 8; bn = (blockIdx.x - 2) * 64;
    P = partE + (size_t)h * (8L * 64 * HID) + (size_t)by * 64 * HID;
  }
  const int fa = (lc & 7) << 2;
  float acc[4][4] = {};
  for (int kt = by; kt < ktiles; kt += nch) {
    const int k0 = kt << 6;
    __syncthreads();
#pragma unroll
    for (int i = 0; i < 4; ++i) {
      const int r = lr + 16 * i;
      const float4 av = *(const float4*)(A + (size_t)r * lda + k0 + lc * 4);
      As[lc * 4 + 0][r ^ fa] = av.x; As[lc * 4 + 1][r ^ fa] = av.y;
      As[lc * 4 + 2][r ^ fa] = av.z; As[lc * 4 + 3][r ^ fa] = av.w;
      const float4 bv = *(const float4*)(Bb + (size_t)(k0 + r) * ldb + bn + lc * 4);
      *(float4*)(&Bs[r][SWZ(r, lc * 4)]) = bv;
    }
    __syncthreads();
#pragma unroll 8
    for (int kk = 0; kk < 64; ++kk) {
      const int fk = ((kk >> 2) & 7) << 2;
      const float4 a = *(const float4*)(&As[kk][(lr * 4) ^ fk]);
      const float4 b = *(const float4*)(&Bs[kk][(lc * 4) ^ fk]);
      acc[0][0] += a.x * b.x; acc[0][1] += a.x * b.y; acc[0][2] += a.x * b.z; acc[0][3] += a.x * b.w;
      acc[1][0] += a.y * b.x; acc[1][1] += a.y * b.y; acc[1][2] += a.y * b.z; acc[1][3] += a.y * b.w;
      acc[2][0] += a.z * b.x; acc[2][1] += a.z * b.y; acc[2][2] += a.z * b.z; acc[2][3] += a.z * b.w;
      acc[3][0] += a.w * b.x; acc[3][1] += a.w * b.y; acc[3][2] += a.w * b.z; acc[3][3] += a.w * b.w;
    }
  }
#pragma unroll
  for (int i = 0; i < 4; ++i)
#pragma unroll
    for (int j = 0; j < 4; ++j)
      P[(size_t)(lr * 4 + i) * N + bn + lc * 4 + j] = acc[i][j];
}

// ---- fused FSMN conv + residuals + x_cat + LN3 (one block per row t) -------
__global__ __launch_bounds__(256) void fsmnln_k(
    const float* __restrict__ y4, const float* __restrict__ lfin,
    const float* __restrict__ cache, const float* __restrict__ fw,
    const float* __restrict__ g, const float* __restrict__ b,
    float* __restrict__ xb, float* __restrict__ xcat,
    float* __restrict__ y1out) {
  __shared__ float buf[HID];
  __shared__ float red[256];
  const int t = blockIdx.x, tid = threadIdx.x;
  float s = 0.f;
  for (int h = tid; h < HID; h += 256) {
    float conv = 0.f;
#pragma unroll
    for (int k = 0; k < KW; ++k) {
      const int j = t + k;
      const float xcv = (j < KW - 1) ? cache[h * (KW - 1) + j]
                                     : y4[(size_t)(j - (KW - 1)) * HID + h];
      conv += xcv * fw[h * KW + k];
    }
    const float yv = y4[(size_t)t * HID + h];
    const float x = conv + yv + lfin[(size_t)t * HID + h];
    xb[(size_t)t * HID + h] = x;
    buf[h] = x; s += x;
    xcat[h * (KW - 1 + TT) + (KW - 1) + t] = yv;
    if (t == 0) {
      for (int j2 = 0; j2 < KW - 1; ++j2)
        xcat[h * (KW - 1 + TT) + j2] = cache[h * (KW - 1) + j2];
    }
  }
  red[tid] = s; __syncthreads();
  for (int st = 128; st > 0; st >>= 1) { if (tid < st) red[tid] += red[tid + st]; __syncthreads(); }
  const float mean = red[0] / HID;
  __syncthreads();
  float vs = 0.f;
  for (int h = tid; h < HID; h += 256) { float d = buf[h] - mean; vs += d * d; }
  red[tid] = vs; __syncthreads();
  for (int st = 128; st > 0; st >>= 1) { if (tid < st) red[tid] += red[tid + st]; __syncthreads(); }
  const float inv = rsqrtf(red[0] / HID + 1e-5f);
  for (int h = tid; h < HID; h += 256)
    y1out[(size_t)t * HID + h] = (buf[h] - mean) * inv * g[h] + b[h];
}

// ---- single-pass LDS row softmax; fused qc-dot + scores-new partial sum ----
__global__ __launch_bounds__(256) void softmax_k(
    float* __restrict__ sc, float* __restrict__ rs,
    const float* __restrict__ qpart, const float* __restrict__ qbi_l,
    const float* __restrict__ kb, const float* __restrict__ partN,
    int cols, int newStart, float alpha) {
  __shared__ float srow[8192];
  __shared__ float red[256];
  const int tid = threadIdx.x;
  const int row = blockIdx.x;
  const int h = row >> 6, t = row & 63;
  sc += (size_t)row * cols;
  const float* pn = partN + (size_t)h * 64 * SEQ + (size_t)t * SEQ;
  float qv = 0.f;
  if (tid < DKH) {
    const float* qp0 = qpart + (size_t)t * HID + h * DKH + tid;
    float q = qp0[0];
    for (int c = 1; c < 8; ++c) q += qp0[(size_t)c * 64 * HID];
    q += qbi_l[h * DKH + tid];
    qv = q * kb[h * DKH + tid];
  }
  red[tid] = qv; __syncthreads();
  for (int st = 64; st > 0; st >>= 1) { if (tid < st) red[tid] += red[tid + st]; __syncthreads(); }
  const float qcv = red[0];
  __syncthreads();
  float m = -3.4e38f;
  for (int c = tid; c < cols; c += 256) {
    float v = sc[c];
    if (c >= newStart) v += pn[c - newStart] + qcv;
    v *= alpha;
    srow[c] = v; m = fmaxf(m, v);
  }
  red[tid] = m; __syncthreads();
  for (int st = 128; st > 0; st >>= 1) { if (tid < st) red[tid] = fmaxf(red[tid], red[tid + st]); __syncthreads(); }
  m = red[0]; __syncthreads();
  float s = 0.f;
  for (int c = tid; c < cols; c += 256) {
    const float e = __expf(srow[c] - m);
    srow[c] = e; s += e;
  }
  red[tid] = s; __syncthreads();
  for (int st = 128; st > 0; st >>= 1) { if (tid < st) red[tid] += red[tid + st]; __syncthreads(); }
  const float inv = 1.f / red[0];
  float ns = 0.f;
  for (int c = tid; c < cols; c += 256) {
    const float p = srow[c] * inv; sc[c] = p;
    if (c >= newStart) ns += p;
  }
  __syncthreads();
  red[tid] = ns; __syncthreads();
  for (int st = 128; st > 0; st >>= 1) { if (tid < st) red[tid] += red[tid + st]; __syncthreads(); }
  if (tid == 0) rs[row] = red[0];
}

// ---- Argmax over vocab: lg = P0 + P1 + bias (vocab splitK2 fold, r20-proven)
__global__ __launch_bounds__(256) void argmax_k(const float* __restrict__ P0,
                                                const float* __restrict__ P1,
                                                const float* __restrict__ bias,
                                                float* __restrict__ out) {
  __shared__ float vs[256];
  __shared__ int ix[256];
  const int tid = threadIdx.x;
  P0 += (size_t)blockIdx.x * VOC;
  P1 += (size_t)blockIdx.x * VOC;
  float bm = -3.4e38f;
  int bi = 0;
  for (int c = tid; c < VOC; c += 256) {
    const float v = P0[c] + P1[c] + bias[c];
    if (v > bm) { bm = v; bi = c; }
  }
  vs[tid] = bm; ix[tid] = bi; __syncthreads();
  for (int st = 128; st > 0; st >>= 1) {
    if (tid < st) {
      if (vs[tid + st] > vs[tid] || (vs[tid + st] == vs[tid] && ix[tid + st] < ix[tid])) {
        vs[tid] = vs[tid + st]; ix[tid] = ix[tid + st];
      }
    }
    __syncthreads();
  }
  if (tid == 0) out[blockIdx.x] = (float)ix[0];
}

// ---------------- save_keys / save_values (runs LAST; overwrites scratch) ---
__global__ __launch_bounds__(256) void kvsave_k(const float* __restrict__ enc,
                                                const float* __restrict__ kvw,
                                                const float* __restrict__ kvb,
                                                float* __restrict__ keys,
                                                float* __restrict__ vals) {
  __shared__ float As[64][64];
  __shared__ float Bs[64][64];
  const int tid = threadIdx.x;
  const int lr = tid >> 4, lc = tid & 15;
  const int bn = blockIdx.x * 64, bm = blockIdx.y * 64;
  const int l = blockIdx.z;
  const float* W = kvw + (size_t)l * HID * 2 * HID;
  const int fa = (lc & 7) << 2;
  float acc[4][4] = {};
  for (int k0 = 0; k0 < HID; k0 += 64) {
    __syncthreads();
#pragma unroll
    for (int i = 0; i < 4; ++i) {
      const int r = lr + 16 * i;
      const float4 av =
          *(const float4*)(enc + (size_t)(SEQ - LBN + bm + r) * HID + k0 + lc * 4);
      As[lc * 4 + 0][r ^ fa] = av.x; As[lc * 4 + 1][r ^ fa] = av.y;
      As[lc * 4 + 2][r ^ fa] = av.z; As[lc * 4 + 3][r ^ fa] = av.w;
      const float4 bv = *(const float4*)(W + (size_t)(k0 + r) * (2 * HID) + bn + lc * 4);
      *(float4*)(&Bs[r][SWZ(r, lc * 4)]) = bv;
    }
    __syncthreads();
#pragma unroll 8
    for (int kk = 0; kk < 64; ++kk) {
      const int fk = ((kk >> 2) & 7) << 2;
      const float4 a = *(const float4*)(&As[kk][(lr * 4) ^ fk]);
      const float4 b = *(const float4*)(&Bs[kk][(lc * 4) ^ fk]);
      acc[0][0] += a.x * b.x; acc[0][1] += a.x * b.y; acc[0][2] += a.x * b.z; acc[0][3] += a.x * b.w;
      acc[1][0] += a.y * b.x; acc[1][1] += a.y * b.y; acc[1][2] += a.y * b.z; acc[1][3] += a.y * b.w;
      acc[2][0] += a.z * b.x; acc[2][1] += a.z * b.y; acc[2][2] += a.z * b.z; acc[2][3] += a.z * b.w;
      acc[3][0] += a.w * b.x; acc[3][1] += a.w * b.y; acc[3][2] += a.w * b.z; acc[3][3] += a.w * b.w;
    }
  }
#pragma unroll
  for (int i = 0; i < 4; ++i) {
    const int m = bm + lr * 4 + i;
#pragma unroll
    for (int j = 0; j < 4; ++j) {
      const int n = bn + lc * 4 + j;
      const float v = acc[i][j] + kvb[(size_t)l * 2 * HID + n];
      if (n < 512) {
        const int h = n >> 7, d = n & 127;
        keys[(((size_t)l * NHD + h) * DKH + d) * LBN + m] = v;
      } else {
        const int c = n - 512, h = c >> 7, d = c & 127;
        vals[(((size_t)l * NHD + h) * LBN + m) * DKH + d] = v;
      }
    }
  }
}

extern "C" void kernel_launch(void* const* d_in, const int* in_sizes, int n_in,
                              void* d_out, int out_size, void* d_ws, size_t ws_size,
                              hipStream_t stream) {
  static const int EXPECT[34] = {
      1048576, 32768, 81920, -1, -1,
      8192, 8192, 8192, 8192, 8192, 8192,
      32768, 32768,
      16777216, 32768, 16777216, 90112,
      4194304, 8192, 8388608, 16384, 4194304, 8192,
      512, 512, 1048576, 2048, 2048, 2048, 1048576,
      512, 512, 4302848, 8404};
  if (out_size != 4800576) {
    diag_k<<<1, 64, 0, stream>>>((float*)d_out, 9800000.f);
    return;
  }
  float* out_fsmn = (float*)d_out;
  float* out_keys = out_fsmn + (size_t)LAY * HID * (KW - 1 + TT);
  float* out_vals = out_keys + (size_t)LAY * NHD * DKH * LBN;
  float* out_ids  = out_vals + (size_t)LAY * NHD * LBN * DKH;
  if (n_in < 34) {
    diag_k<<<1, 64, 0, stream>>>(out_ids, 9900000.f);
    return;
  }
  for (int i = 0; i < 34; ++i) {
    if (EXPECT[i] >= 0 && in_sizes[i] != EXPECT[i]) {
      diag_k<<<1, 64, 0, stream>>>(out_ids, (float)((i + 1) * 100000));
      return;
    }
  }
  const long per = (long)LAY * NHD * DKH;
  const long ckl = (long)in_sizes[3] / per;
  if ((long)in_sizes[3] != ckl * per || in_sizes[4] != in_sizes[3] ||
      ckl <= 0 || (ckl & 63) != 0 || ckl > 6144) {
    diag_k<<<1, 64, 0, stream>>>(out_fsmn, (float)in_sizes[3]);
    return;
  }
  // d_ws: partials (10 MB) + vocab partials (4.3 MB); r12 proved ws >= 33.5 MB
  if (ws_size < (size_t)3697152 * 4) {
    diag_k<<<1, 64, 0, stream>>>(out_fsmn, 1.0e6f + (float)(ws_size >> 20));
    return;
  }
  const int ckv = (int)ckl;
  const int sct = ckv + SEQ;
  const long TS = (long)TT * sct;
  const int ncho = (ckv / 64 < 8) ? (ckv / 64) : 8;

  const float* enc    = (const float*)d_in[0];
  const float* lfrm   = (const float*)d_in[1];
  const float* fcache = (const float*)d_in[2];
  const float* kcache = (const float*)d_in[3];
  const float* vcache = (const float*)d_in[4];
  const float* n1g = (const float*)d_in[5];  const float* n1b = (const float*)d_in[6];
  const float* n2g = (const float*)d_in[7];  const float* n2b = (const float*)d_in[8];
  const float* n3g = (const float*)d_in[9];  const float* n3b = (const float*)d_in[10];
  const float* fng = (const float*)d_in[11]; const float* fnb = (const float*)d_in[12];
  const float* w1  = (const float*)d_in[13]; const float* b1  = (const float*)d_in[14];
  const float* w2  = (const float*)d_in[15];
  const float* fw  = (const float*)d_in[16];
  const float* qw  = (const float*)d_in[17]; const float* qbi  = (const float*)d_in[18];
  const float* kvw = (const float*)d_in[19]; const float* kvbi = (const float*)d_in[20];
  const float* ow  = (const float*)d_in[21]; const float* obi  = (const float*)d_in[22];
  const float* d3n1g = (const float*)d_in[23]; const float* d3n1b = (const float*)d_in[24];
  const float* d3w1  = (const float*)d_in[25]; const float* d3b1  = (const float*)d_in[26];
  const float* d3fng = (const float*)d_in[27]; const float* d3fnb = (const float*)d_in[28];
  const float* d3w2  = (const float*)d_in[29];
  const float* ang   = (const float*)d_in[30]; const float* anb = (const float*)d_in[31];
  const float* outw  = (const float*)d_in[32]; const float* outb = (const float*)d_in[33];

  // d_out scratch (proven r19 layout); keys/vals overwritten by kvsave_k last
  float* sc  = out_keys;
  float* ov  = out_vals;
  float* lf  = ov + 0;
  float* y1  = ov + 32768;
  float* y4  = ov + 98304;
  float* xb  = ov + 131072;
  float* y2  = ov + 360448;
  float* qp  = ov + 491520;
  float* rs  = ov + 753920;
  // d_ws: split-K partials + vocab partials
  float* wsf   = (float*)d_ws;
  float* part  = wsf;
  float* part2 = wsf + 524288;
  float* partE = wsf + 1048576;
  float* partN = wsf + 2097152;
  float* vp    = wsf + 2621440;   // 2 * 64 * VOC = 1075712 floats

  const float alpha = 0.08838834764831845f;
  const long TH = (long)TT * HID;
  const long pz_ctx = (long)(ncho + 4) * 64 * DKH;

  redln_k<<<TT, 256, 0, stream>>>(lfrm, HID, 1, nullptr, nullptr, 0,
                                  n1g, n1b, lf, y1);

  for (int l = 0; l < LAY; ++l) {
    const float* Wkv = kvw + (size_t)l * HID * 2 * HID;
    const float* Bkv = kvbi + (size_t)l * 2 * HID;
    const float* qbi_l = qbi + (size_t)l * HID;
    gemm32_nn<<<dim3(64, 8, 1), 256, 0, stream>>>(
        y1, HID, 0, w1 + (size_t)l * HID * FF, FF, 0, FF, HID, 8, part2, 0, 0,
        1, 0, nullptr, nullptr, 0);
    redln_k<<<TT, 256, 0, stream>>>(part2, FF, 8, b1 + (size_t)l * FF, nullptr, 1,
                                    fng + (size_t)l * FF, fnb + (size_t)l * FF,
                                    nullptr, y2);
    gemm32_nn<<<dim3(16, 32, 1), 256, 0, stream>>>(
        y2, FF, 0, w2 + (size_t)l * FF * HID, HID, 0, HID, FF, 32, part2, 0, 0,
        1, 0, nullptr, nullptr, 0);
    redln_k<<<TT, 256, 0, stream>>>(part2, HID, 32, nullptr, nullptr, 0,
                                    n2g + l * HID, n2b + l * HID, nullptr, y4);
    fsmnln_k<<<TT, 256, 0, stream>>>(y4, lf, fcache + (size_t)l * HID * (KW - 1),
                                     fw + (size_t)l * HID * KW,
                                     n3g + l * HID, n3b + l * HID,
                                     xb, out_fsmn + (size_t)l * HID * (KW - 1 + TT), y1);
    gemm32_nn<<<dim3(16, 8, 1), 256, 0, stream>>>(
        y1, HID, 0, qw + (size_t)l * HID * HID, HID, 0, HID, HID, 8, part2, 0, 0,
        1, 0, nullptr, nullptr, 0);
    attn1_k<<<dim3(8 + ckv / 64, 1, NHD), 256, 0, stream>>>(
        part2, qbi_l, Wkv, kcache + (size_t)l * NHD * DKH * ckv, qp, sc, ckv, sct);
    gemm_nt<<<dim3(32, 2, NHD), 256, 0, stream>>>(
        qp, HID, TH, enc, HID, 0, sc + ckv, sct, TS, SEQ, HID, 2, partN);
    softmax_k<<<NHD * TT, 256, 0, stream>>>(sc, rs, part2, qbi_l, Bkv, partN,
                                            sct, ckv, alpha);
    attn2_k<<<dim3(10, 8, NHD), 256, 0, stream>>>(
        sc, vcache + (size_t)l * NHD * ckv * DKH, enc, part, partE,
        ckv, sct, ncho, pz_ctx);
    gemm32_nn<<<dim3(4, 4, NHD), 256, 0, stream>>>(
        partE, HID, 8L * 64 * HID, Wkv + HID, 2 * HID, DKH, DKH, HID, 4,
        part, pz_ctx, ncho, 8, 64L * HID, nullptr, nullptr, 0);
    gemm32_nn<<<dim3(16, 8, 1), 256, 0, stream>>>(
        part, 0, 0, ow + (size_t)l * HID * HID, HID, 0, HID, HID, 8, part2, 0, 0,
        ncho + 4, 8192, rs, Bkv + HID, pz_ctx);
    const float* ng = (l + 1 < LAY) ? n1g + (l + 1) * HID : d3n1g;
    const float* nb = (l + 1 < LAY) ? n1b + (l + 1) * HID : d3n1b;
    redln_k<<<TT, 256, 0, stream>>>(part2, HID, 8, obi + (size_t)l * HID, xb, 0,
                                    ng, nb, lf, y1);
  }

  // ---- final decoder3 block + vocab (splitK2) + argmax (folds sum+bias) ----
  gemm32_nn<<<dim3(64, 8, 1), 256, 0, stream>>>(
      y1, HID, 0, d3w1, FF, 0, FF, HID, 8, part2, 0, 0, 1, 0, nullptr, nullptr, 0);
  redln_k<<<TT, 256, 0, stream>>>(part2, FF, 8, d3b1, nullptr, 1,
                                  d3fng, d3fnb, nullptr, y2);
  gemm32_nn<<<dim3(16, 32, 1), 256, 0, stream>>>(
      y2, FF, 0, d3w2, HID, 0, HID, FF, 32, part2, 0, 0, 1, 0, nullptr, nullptr, 0);
  redln_k<<<TT, 256, 0, stream>>>(part2, HID, 32, nullptr, nullptr, 0,
                                  ang, anb, nullptr, y4);
  gemm_nn<<<dim3((VOC + 63) / 64, 2, 1), 256, 0, stream>>>(
      y4, HID, 0, outw, VOC, 0, nullptr, 0, 0, nullptr, nullptr, 0,
      VOC, HID, 0, 2, vp, 0, 0, 1, 0);
  argmax_k<<<TT, 256, 0, stream>>>(vp, vp + 64L * VOC, outb, out_ids);

  // ---- LAST: overwrite scratch regions with real save_keys / save_values ---
  kvsave_k<<<dim3(2 * HID / 64, LBN / 64, LAY), 256, 0, stream>>>(
      enc, kvw, kvbi, out_keys, out_vals);
}